// Round 4
// baseline (995.007 us; speedup 1.0000x reference)
//
#include <hip/hip_runtime.h>

#define NN 50000
#define NE 800000
#define HD 128
#define FED 16
#define MFD 273
#define K1 288     // padded K for GEMM1 (9 x 32)
#define NO1 256    // GEMM1 output cols (c1 | m1)
#define FSTR 296   // LDS row stride (ushorts) for f / cm buffer
#define NFSTR 264  // node kernel f stride
#define NNSTR 136  // node kernel n1 stride

typedef __bf16 bf16x8 __attribute__((ext_vector_type(8)));
typedef float f32x4 __attribute__((ext_vector_type(4)));
typedef unsigned short u16;

__device__ __forceinline__ u16 f2b(float x) {
  unsigned u = __builtin_bit_cast(unsigned, x);
  return (u16)((u + 0x7FFFu + ((u >> 16) & 1u)) >> 16);  // RNE
}
__device__ __forceinline__ float siluf(float x) { return x / (1.f + __expf(-x)); }

// ---------------- weight packing: f32 [k][n] -> bf16 [n][k] ----------------
__global__ void pack_weights(const float* __restrict__ wc1, const float* __restrict__ we1,
                             const float* __restrict__ wc2, const float* __restrict__ we2,
                             const float* __restrict__ wn1, const float* __restrict__ wn2,
                             u16* __restrict__ W1t, u16* __restrict__ W2ct,
                             u16* __restrict__ W2mt, u16* __restrict__ Wn1t,
                             u16* __restrict__ Wn2t) {
  int i = blockIdx.x * 256 + threadIdx.x;
  if (i < 256 * K1) {                       // W1t: [256][288]
    int n = i / K1, k = i - n * K1;
    float v = 0.f;
    if (k < MFD) v = (n < HD) ? wc1[k * HD + n] : we1[k * HD + (n - HD)];
    W1t[i] = f2b(v);
    return;
  }
  int j = i - 256 * K1;
  if (j < HD * HD) {                        // W2ct / W2mt: [128][128]
    int n = j >> 7, k = j & 127;
    W2ct[j] = f2b(wc2[k * HD + n]);
    W2mt[j] = f2b(we2[k * HD + n]);
    return;
  }
  j -= HD * HD;
  if (j < HD * 256) {                       // Wn1t: [128][256]
    int n = j >> 8, k = j & 255;
    Wn1t[j] = f2b(wn1[k * HD + n]);
    return;
  }
  j -= HD * 256;
  if (j < HD * HD) {                        // Wn2t: [128][128]
    int n = j >> 7, k = j & 127;
    Wn2t[j] = f2b(wn2[k * HD + n]);
  }
}

// ---------------- fused edge kernel ----------------
// 128 edges per block, 4 waves, each wave owns 32 edge rows end-to-end.
__global__ __launch_bounds__(256, 2) void edge_kernel(
    const float* __restrict__ h, const float* __restrict__ coords,
    const float* __restrict__ a, const int* __restrict__ src,
    const int* __restrict__ dst,
    const float* __restrict__ bc1, const float* __restrict__ be1,
    const float* __restrict__ bc2, const float* __restrict__ be2,
    const float* __restrict__ wc3, const float* __restrict__ wa,
    const float* __restrict__ ba,
    const u16* __restrict__ W1t, const u16* __restrict__ W2ct,
    const u16* __restrict__ W2mt,
    float* __restrict__ x_agg, float* __restrict__ h_agg) {
  __shared__ u16 fL[128 * FSTR];   // f (bf16), later reused as [c1|m1]
  __shared__ float diffL[128][3];
  __shared__ float radL[128];
  __shared__ int dstL[128];

  const int tid = threadIdx.x;
  const int wave = tid >> 6;
  const int lane = tid & 63;
  const int wrow = wave * 32;
  const int ebase = blockIdx.x * 128;

  // ---------- gather (per-wave private rows; no barriers anywhere) ----------
  {
    const int r = wrow + (lane >> 1);
    const int q = lane & 1;
    const int e = ebase + r;
    const int s = src[e];
    const int d = dst[e];
    const float4* hs4 = (const float4*)(h + (size_t)s * HD) + q * 16;
    const float4* hd4 = (const float4*)(h + (size_t)d * HD) + q * 16;
    u16* frow = &fL[r * FSTR];
#pragma unroll
    for (int u = 0; u < 16; ++u) {
      float4 v = hs4[u];
      ushort4 b; b.x = f2b(v.x); b.y = f2b(v.y); b.z = f2b(v.z); b.w = f2b(v.w);
      *(ushort4*)(frow + q * 64 + u * 4) = b;
    }
#pragma unroll
    for (int u = 0; u < 16; ++u) {
      float4 v = hd4[u];
      ushort4 b; b.x = f2b(v.x); b.y = f2b(v.y); b.z = f2b(v.z); b.w = f2b(v.w);
      *(ushort4*)(frow + HD + q * 64 + u * 4) = b;
    }
    if (q == 0) {
      float dx = coords[(size_t)s * 3 + 0] - coords[(size_t)d * 3 + 0];
      float dy = coords[(size_t)s * 3 + 1] - coords[(size_t)d * 3 + 1];
      float dz = coords[(size_t)s * 3 + 2] - coords[(size_t)d * 3 + 2];
      float rad = dx * dx + dy * dy + dz * dz;
      diffL[r][0] = dx; diffL[r][1] = dy; diffL[r][2] = dz;
      radL[r] = rad; dstL[r] = d;
      frow[256] = f2b(rad);
    } else {
      const float* ap = a + (size_t)e * FED;
#pragma unroll
      for (int u = 0; u < FED; ++u) frow[257 + u] = f2b(ap[u]);
#pragma unroll
      for (int u = MFD; u < K1; ++u) frow[u] = 0;
    }
  }

  const int ln = lane & 15;
  const int khi = lane >> 4;

  // ---------- hoist A1 fragments (f is dead in LDS afterwards) ----------
  bf16x8 a1[2][9];
#pragma unroll
  for (int st = 0; st < 2; ++st)
#pragma unroll
    for (int kk = 0; kk < 9; ++kk)
      a1[st][kk] = *(const bf16x8*)&fL[(wrow + st * 16 + ln) * FSTR + kk * 32 + khi * 8];

  // ---------- GEMM1: [32 x 288] @ [288 x 256] + bias, silu -> cm in LDS ----------
#pragma unroll 2
  for (int nt = 0; nt < 16; ++nt) {
    const int col = nt * 16 + ln;
    const float b0 = (col < HD) ? bc1[col] : be1[col - HD];
    f32x4 acc0 = {b0, b0, b0, b0};
    f32x4 acc1 = {b0, b0, b0, b0};
    const u16* wp = &W1t[(size_t)col * K1];
#pragma unroll
    for (int kk = 0; kk < 9; ++kk) {
      bf16x8 bf = *(const bf16x8*)(wp + kk * 32 + khi * 8);
      acc0 = __builtin_amdgcn_mfma_f32_16x16x32_bf16(a1[0][kk], bf, acc0, 0, 0, 0);
      acc1 = __builtin_amdgcn_mfma_f32_16x16x32_bf16(a1[1][kk], bf, acc1, 0, 0, 0);
    }
#pragma unroll
    for (int i = 0; i < 4; ++i) {
      fL[(wrow + khi * 4 + i) * FSTR + col] = f2b(siluf(acc0[i]));
      fL[(wrow + 16 + khi * 4 + i) * FSTR + col] = f2b(siluf(acc1[i]));
    }
  }

  // ---------- A2 fragments from cm ----------
  bf16x8 a2c[2][4], a2m[2][4];
#pragma unroll
  for (int st = 0; st < 2; ++st)
#pragma unroll
    for (int kk = 0; kk < 4; ++kk) {
      a2c[st][kk] = *(const bf16x8*)&fL[(wrow + st * 16 + ln) * FSTR + kk * 32 + khi * 8];
      a2m[st][kk] = *(const bf16x8*)&fL[(wrow + st * 16 + ln) * FSTR + HD + kk * 32 + khi * 8];
    }

  // ---------- GEMM2 (c2, m2) + per-row dots ----------
  f32x4 m2s0[8], m2s1[8];
  f32x4 pscale0 = {0, 0, 0, 0}, pscale1 = {0, 0, 0, 0};
  f32x4 patt0 = {0, 0, 0, 0}, patt1 = {0, 0, 0, 0};
#pragma unroll
  for (int nt = 0; nt < 8; ++nt) {
    const int col = nt * 16 + ln;
    const float w3 = wc3[col];
    const float wav = wa[col];
    const float bc2v = bc2[col];
    const float be2v = be2[col];
    f32x4 ac0 = {bc2v, bc2v, bc2v, bc2v}, ac1 = {bc2v, bc2v, bc2v, bc2v};
    f32x4 am0 = {be2v, be2v, be2v, be2v}, am1 = {be2v, be2v, be2v, be2v};
    const u16* wpc = &W2ct[(size_t)col * HD];
    const u16* wpm = &W2mt[(size_t)col * HD];
#pragma unroll
    for (int kk = 0; kk < 4; ++kk) {
      bf16x8 bc = *(const bf16x8*)(wpc + kk * 32 + khi * 8);
      bf16x8 bm = *(const bf16x8*)(wpm + kk * 32 + khi * 8);
      ac0 = __builtin_amdgcn_mfma_f32_16x16x32_bf16(a2c[0][kk], bc, ac0, 0, 0, 0);
      ac1 = __builtin_amdgcn_mfma_f32_16x16x32_bf16(a2c[1][kk], bc, ac1, 0, 0, 0);
      am0 = __builtin_amdgcn_mfma_f32_16x16x32_bf16(a2m[0][kk], bm, am0, 0, 0, 0);
      am1 = __builtin_amdgcn_mfma_f32_16x16x32_bf16(a2m[1][kk], bm, am1, 0, 0, 0);
    }
#pragma unroll
    for (int i = 0; i < 4; ++i) {
      float c0 = siluf(ac0[i]); pscale0[i] += c0 * w3;
      float c1 = siluf(ac1[i]); pscale1[i] += c1 * w3;
      float m0 = siluf(am0[i]); patt0[i] += m0 * wav; am0[i] = m0;
      float m1 = siluf(am1[i]); patt1[i] += m1 * wav; am1[i] = m1;
    }
    m2s0[nt] = am0;
    m2s1[nt] = am1;
  }

  // ---------- butterfly reduce over the 16 lanes sharing khi ----------
#pragma unroll
  for (int off = 1; off < 16; off <<= 1) {
#pragma unroll
    for (int i = 0; i < 4; ++i) {
      pscale0[i] += __shfl_xor(pscale0[i], off);
      pscale1[i] += __shfl_xor(pscale1[i], off);
      patt0[i] += __shfl_xor(patt0[i], off);
      patt1[i] += __shfl_xor(patt1[i], off);
    }
  }

  // ---------- coord messages (3 atomics per edge) ----------
  if (ln < 3) {
#pragma unroll
    for (int i = 0; i < 4; ++i) {
      int r0 = wrow + khi * 4 + i;
      int r1 = r0 + 16;
      float v0 = pscale0[i] * diffL[r0][ln] / (radL[r0] + 1.f);
      float v1 = pscale1[i] * diffL[r1][ln] / (radL[r1] + 1.f);
      atomicAdd(&x_agg[(size_t)dstL[r0] * 3 + ln], v0);
      atomicAdd(&x_agg[(size_t)dstL[r1] * 3 + ln], v1);
    }
  }

  // ---------- attention gate + hidden messages (128 atomics per edge) ----------
  const float bav = ba[0];
  f32x4 att0, att1;
  size_t hb0[4], hb1[4];
#pragma unroll
  for (int i = 0; i < 4; ++i) {
    att0[i] = 1.f / (1.f + __expf(-(patt0[i] + bav)));
    att1[i] = 1.f / (1.f + __expf(-(patt1[i] + bav)));
    hb0[i] = (size_t)dstL[wrow + khi * 4 + i] * HD;
    hb1[i] = (size_t)dstL[wrow + 16 + khi * 4 + i] * HD;
  }
#pragma unroll
  for (int nt = 0; nt < 8; ++nt) {
    const int col = nt * 16 + ln;
#pragma unroll
    for (int i = 0; i < 4; ++i) {
      atomicAdd(&h_agg[hb0[i] + col], att0[i] * m2s0[nt][i]);
      atomicAdd(&h_agg[hb1[i] + col], att1[i] * m2s1[nt][i]);
    }
  }
}

// ---------------- node kernel: node MLP + residual + coords ----------------
__global__ __launch_bounds__(256, 2) void node_kernel(
    const float* __restrict__ h, const float* __restrict__ coords,
    const float* __restrict__ bn1, const float* __restrict__ bn2,
    const u16* __restrict__ Wn1t, const u16* __restrict__ Wn2t,
    const float* __restrict__ x_agg, const float* __restrict__ h_agg,
    float* __restrict__ out) {
  __shared__ u16 fL[64 * NFSTR];
  __shared__ u16 nL[64 * NNSTR];
  const int tid = threadIdx.x;
  const int wave = tid >> 6;
  const int lane = tid & 63;
  const int nbase = blockIdx.x * 64;

  // coords_out = coords + x_agg
  if (tid < 192) {
    int idx = nbase * 3 + tid;
    if (idx < NN * 3) out[(size_t)NN * HD + idx] = coords[idx] + x_agg[idx];
  }

  const int wrow = wave * 16;
  {
    const int r = wrow + (lane >> 2);
    const int q = lane & 3;
    const int node = nbase + r;
    const int nn = (node < NN) ? node : 0;
    const float4* hp = (const float4*)(h + (size_t)nn * HD) + q * 8;
    const float4* gp = (const float4*)(h_agg + (size_t)nn * HD) + q * 8;
    u16* frow = &fL[r * NFSTR];
#pragma unroll
    for (int u = 0; u < 8; ++u) {
      float4 v = hp[u];
      ushort4 b; b.x = f2b(v.x); b.y = f2b(v.y); b.z = f2b(v.z); b.w = f2b(v.w);
      *(ushort4*)(frow + q * 32 + u * 4) = b;
      float4 w = gp[u];
      ushort4 c; c.x = f2b(w.x); c.y = f2b(w.y); c.z = f2b(w.z); c.w = f2b(w.w);
      *(ushort4*)(frow + HD + q * 32 + u * 4) = c;
    }
  }

  const int ln = lane & 15;
  const int khi = lane >> 4;

  bf16x8 a1[8];
#pragma unroll
  for (int kk = 0; kk < 8; ++kk)
    a1[kk] = *(const bf16x8*)&fL[(wrow + ln) * NFSTR + kk * 32 + khi * 8];

#pragma unroll 2
  for (int nt = 0; nt < 8; ++nt) {
    const int col = nt * 16 + ln;
    const float b = bn1[col];
    f32x4 acc = {b, b, b, b};
    const u16* wp = &Wn1t[(size_t)col * 256];
#pragma unroll
    for (int kk = 0; kk < 8; ++kk) {
      bf16x8 bf = *(const bf16x8*)(wp + kk * 32 + khi * 8);
      acc = __builtin_amdgcn_mfma_f32_16x16x32_bf16(a1[kk], bf, acc, 0, 0, 0);
    }
#pragma unroll
    for (int i = 0; i < 4; ++i)
      nL[(wrow + khi * 4 + i) * NNSTR + col] = f2b(siluf(acc[i]));
  }

  bf16x8 a2[4];
#pragma unroll
  for (int kk = 0; kk < 4; ++kk)
    a2[kk] = *(const bf16x8*)&nL[(wrow + ln) * NNSTR + kk * 32 + khi * 8];

#pragma unroll 2
  for (int nt = 0; nt < 8; ++nt) {
    const int col = nt * 16 + ln;
    const float b = bn2[col];
    f32x4 acc = {b, b, b, b};
    const u16* wp = &Wn2t[(size_t)col * HD];
#pragma unroll
    for (int kk = 0; kk < 4; ++kk) {
      bf16x8 bf = *(const bf16x8*)(wp + kk * 32 + khi * 8);
      acc = __builtin_amdgcn_mfma_f32_16x16x32_bf16(a2[kk], bf, acc, 0, 0, 0);
    }
#pragma unroll
    for (int i = 0; i < 4; ++i) {
      const int node = nbase + wrow + khi * 4 + i;
      if (node < NN)
        out[(size_t)node * HD + col] = h[(size_t)node * HD + col] + acc[i];
    }
  }
}

// ---------------- launch ----------------
extern "C" void kernel_launch(void* const* d_in, const int* in_sizes, int n_in,
                              void* d_out, int out_size, void* d_ws, size_t ws_size,
                              hipStream_t stream) {
  const float* h = (const float*)d_in[0];
  const float* coords = (const float*)d_in[1];
  const float* a = (const float*)d_in[2];
  const int* src = (const int*)d_in[3];
  const int* dst = (const int*)d_in[4];
  const float* wc1 = (const float*)d_in[5];
  const float* bc1 = (const float*)d_in[6];
  const float* wc2 = (const float*)d_in[7];
  const float* bc2 = (const float*)d_in[8];
  const float* wc3 = (const float*)d_in[9];
  const float* we1 = (const float*)d_in[10];
  const float* be1 = (const float*)d_in[11];
  const float* we2 = (const float*)d_in[12];
  const float* be2 = (const float*)d_in[13];
  const float* wa = (const float*)d_in[14];
  const float* ba = (const float*)d_in[15];
  const float* wn1 = (const float*)d_in[16];
  const float* bn1 = (const float*)d_in[17];
  const float* wn2 = (const float*)d_in[18];
  const float* bn2 = (const float*)d_in[19];
  float* out = (float*)d_out;

  char* ws = (char*)d_ws;
  // layout (bytes):
  const size_t OFF_XAGG = 0;                      // NN*3*4      = 600000
  const size_t OFF_HAGG = 600064;                 // NN*128*4    = 25600000
  const size_t OFF_W1T = 26200064;                // 256*288*2   = 147456
  const size_t OFF_W2CT = 26347520;               // 128*128*2   = 32768
  const size_t OFF_W2MT = 26380288;               // 32768
  const size_t OFF_WN1T = 26413056;               // 128*256*2   = 65536
  const size_t OFF_WN2T = 26478592;               // 32768 -> end 26511360

  float* x_agg = (float*)(ws + OFF_XAGG);
  float* h_agg = (float*)(ws + OFF_HAGG);
  u16* W1t = (u16*)(ws + OFF_W1T);
  u16* W2ct = (u16*)(ws + OFF_W2CT);
  u16* W2mt = (u16*)(ws + OFF_W2MT);
  u16* Wn1t = (u16*)(ws + OFF_WN1T);
  u16* Wn2t = (u16*)(ws + OFF_WN2T);

  // zero the aggregation buffers (x_agg .. h_agg end)
  (void)hipMemsetAsync(ws, 0, OFF_W1T, stream);

  pack_weights<<<544, 256, 0, stream>>>(wc1, we1, wc2, we2, wn1, wn2,
                                        W1t, W2ct, W2mt, Wn1t, Wn2t);

  edge_kernel<<<NE / 128, 256, 0, stream>>>(h, coords, a, src, dst,
                                            bc1, be1, bc2, be2, wc3, wa, ba,
                                            W1t, W2ct, W2mt, x_agg, h_agg);

  node_kernel<<<(NN + 63) / 64, 256, 0, stream>>>(h, coords, bn1, bn2,
                                                  Wn1t, Wn2t, x_agg, h_agg, out);
}